// Round 7
// baseline (136.136 us; speedup 1.0000x reference)
//
#include <hip/hip_runtime.h>

typedef __bf16 bf16;
typedef unsigned short u16;
typedef __attribute__((ext_vector_type(8))) __bf16 bf16x8;
typedef __attribute__((ext_vector_type(16))) float f32x16;
typedef __attribute__((ext_vector_type(2))) unsigned int uint2v;
typedef __attribute__((ext_vector_type(4))) unsigned int uint4v;

#define MFMA32(a, b, c) __builtin_amdgcn_mfma_f32_32x32x16_bf16(a, b, c, 0, 0, 0)

__device__ __forceinline__ u16 bbits(float f) {
  bf16 h = (bf16)f;
  return __builtin_bit_cast(u16, h);
}
__device__ __forceinline__ float bf2f(u16 u) {
  return (float)__builtin_bit_cast(bf16, u);
}
__device__ __forceinline__ bf16x8 ldg16(const u16* p) {
  return *reinterpret_cast<const bf16x8*>(p);  // 16B-aligned by construction
}
// 8-byte-aligned read of 8 bf16 as two b64s (for 8B-aligned LDS rows)
__device__ __forceinline__ bf16x8 ld_p8(const u16* p) {
  uint2v a = *reinterpret_cast<const uint2v*>(p);
  uint2v b = *reinterpret_cast<const uint2v*>(p + 4);
  uint4v u;
  u.x = a.x; u.y = a.y; u.z = b.x; u.w = b.y;
  return __builtin_bit_cast(bf16x8, u);
}
__device__ __forceinline__ unsigned packbf(float a, float b) {
  return (unsigned)bbits(a) | ((unsigned)bbits(b) << 16);
}
// split 8 fp32 into hi/lo bf16x8 fragments
__device__ __forceinline__ void split8(const float* xv, bf16x8& hi, bf16x8& lo) {
  uint4v hv, lv;
#pragma unroll
  for (int jp = 0; jp < 4; ++jp) {
    float a0 = xv[2 * jp], a1 = xv[2 * jp + 1];
    u16 h0 = bbits(a0), h1 = bbits(a1);
    u16 l0 = bbits(a0 - bf2f(h0)), l1 = bbits(a1 - bf2f(h1));
    unsigned hh = (unsigned)h0 | ((unsigned)h1 << 16);
    unsigned ll = (unsigned)l0 | ((unsigned)l1 << 16);
    if (jp == 0) { hv.x = hh; lv.x = ll; }
    else if (jp == 1) { hv.y = hh; lv.y = ll; }
    else if (jp == 2) { hv.z = hh; lv.z = ll; }
    else { hv.w = hh; lv.w = ll; }
  }
  hi = __builtin_bit_cast(bf16x8, hv);
  lo = __builtin_bit_cast(bf16x8, lv);
}

// ===========================================================================
// SWIZZLED ("fragment-order") layouts — every MFMA fragment load is
// ldg16(base + (frag*64 + lane)*8): 64 lanes x 16B contiguous = coalesced.
//  K/Q planes (per b):  [tile n32][kc 0..3][lane][j]: pos=tile*32+(lane&31),
//     ch = kc*16+(lane>>5)*8+j
//  V plane (per b): [tile n32][kch][cbi][lane][j]: c=cbi*32+(lane&31),
//     n = tile*32+kch*16+(lane>>5)*8+j
//  theta/phi weights: [s*2+h][lane][j]; conv Wt: [s3dx][kc][cbi][lane][j]
// ===========================================================================

__global__ __launch_bounds__(256) void pa_prep(
    const float* __restrict__ cw, const float* __restrict__ cbias,
    const float* __restrict__ gamma, const float* __restrict__ beta,
    const float* __restrict__ mean, const float* __restrict__ var,
    const float* __restrict__ tw, const float* __restrict__ pw, const float* __restrict__ gw,
    u16* __restrict__ Wt, float* __restrict__ bnA, float* __restrict__ bnB,
    u16* __restrict__ Wth, u16* __restrict__ Wtl,
    u16* __restrict__ Wph, u16* __restrict__ Wpl,
    u16* __restrict__ Wgh, u16* __restrict__ Wgl) {
  int i = blockIdx.x * 256 + threadIdx.x;
  if (i < 36864) {
    int ci = i & 63, co = (i >> 6) & 63, s = i >> 12;  // s = dy*3+dx
    int kc = ci >> 4, q2c = (ci >> 3) & 1, j = ci & 7;
    int lane = q2c * 32 + (co & 31);
    int cbi = co >> 5;
    // fragment order for conv A-operand: coalesced ldg16 in pa_conv
    Wt[(((s * 4 + kc) * 2 + cbi) * 64 + lane) * 8 + j] = bbits(cw[(co * 64 + ci) * 9 + s]);
  }
  if (i < 16384) {  // theta/phi swizzle, 8192 each
    int ii = i & 8191;
    int j = ii & 7, l = (ii >> 3) & 63, f = ii >> 9;  // f = s*2+h
    int out = (f & 1) * 32 + (l & 31);
    int in = (f >> 1) * 16 + (l >> 5) * 8 + j;
    const float* W = (i < 8192) ? tw : pw;
    float v = W[out * 128 + in];
    u16 h = bbits(v);
    u16 lo = bbits(v - bf2f(h));
    if (i < 8192) { Wth[ii] = h; Wtl[ii] = lo; }
    else { Wph[ii] = h; Wpl[ii] = lo; }
  } else if (i < 20480) {  // g swizzle, 4096
    int ii = i - 16384;
    int j = ii & 7, l = (ii >> 3) & 63, f = ii >> 9;  // f = s*2+h, s 0..3
    int out = (f & 1) * 32 + (l & 31);
    int in = (f >> 1) * 16 + (l >> 5) * 8 + j;
    float v = gw[out * 64 + in];
    u16 h = bbits(v);
    Wgh[ii] = h;
    Wgl[ii] = bbits(v - bf2f(h));
  }
  if (i < 64) {
    float rs = rsqrtf(var[i] + 1e-5f);
    float A = gamma[i] * rs;
    bnA[i] = A;
    bnB[i] = (cbias[i] - mean[i]) * A + beta[i];
  }
}

// ---------------------------------------------------------------------------
// Projections v3: grid 512 = (b, tile32), 6 waves = 3 roles x 2 k-halves.
// Each k-half wave computes the partial GEMM over half the input channels;
// pair-merge via LDS, even wave stores. 3072 waves = 3/SIMD.
// theta/g 2-term split, phi 3-term. Fragment-order weights & outputs.
// ---------------------------------------------------------------------------
template <bool LO>
__device__ __forceinline__ void store_qk_swz(const f32x16& a0, const f32x16& a1,
                                             const float* __restrict__ bias,
                                             u16* __restrict__ Hi, u16* __restrict__ Lo,
                                             int base, int l31, int q2) {
#pragma unroll
  for (int mt = 0; mt < 2; ++mt) {
    const f32x16& A = mt ? a1 : a0;
#pragma unroll
    for (int rq = 0; rq < 4; ++rq) {
      int ch = mt * 32 + rq * 8 + q2 * 4;
      float4 bb = *reinterpret_cast<const float4*>(bias + ch);
      float v0 = A[rq * 4 + 0] + bb.x;
      float v1 = A[rq * 4 + 1] + bb.y;
      float v2 = A[rq * 4 + 2] + bb.z;
      float v3 = A[rq * 4 + 3] + bb.w;
      int off = base + ((mt * 2 + (rq >> 1)) * 64 + l31 + 32 * (rq & 1)) * 8 + q2 * 4;
      u16 h0 = bbits(v0), h1 = bbits(v1), h2 = bbits(v2), h3 = bbits(v3);
      uint2v hv;
      hv.x = (unsigned)h0 | ((unsigned)h1 << 16);
      hv.y = (unsigned)h2 | ((unsigned)h3 << 16);
      *reinterpret_cast<uint2v*>(Hi + off) = hv;
      if (LO) {
        u16 l0 = bbits(v0 - bf2f(h0)), l1 = bbits(v1 - bf2f(h1));
        u16 l2 = bbits(v2 - bf2f(h2)), l3 = bbits(v3 - bf2f(h3));
        uint2v lv;
        lv.x = (unsigned)l0 | ((unsigned)l1 << 16);
        lv.y = (unsigned)l2 | ((unsigned)l3 << 16);
        *reinterpret_cast<uint2v*>(Lo + off) = lv;
      }
    }
  }
}

template <int NS>
__device__ __forceinline__ void gemm3(const u16* __restrict__ Wh, const u16* __restrict__ Wl,
                                      const bf16x8* Bh, const bf16x8* Bl,
                                      int lane, f32x16& a0, f32x16& a1) {
#pragma unroll
  for (int s = 0; s < NS; ++s) {
    bf16x8 w0h = ldg16(Wh + ((s * 2 + 0) * 64 + lane) * 8);
    bf16x8 w0l = ldg16(Wl + ((s * 2 + 0) * 64 + lane) * 8);
    bf16x8 w1h = ldg16(Wh + ((s * 2 + 1) * 64 + lane) * 8);
    bf16x8 w1l = ldg16(Wl + ((s * 2 + 1) * 64 + lane) * 8);
    a0 = MFMA32(w0h, Bh[s], a0);
    a0 = MFMA32(w0h, Bl[s], a0);
    a0 = MFMA32(w0l, Bh[s], a0);
    a1 = MFMA32(w1h, Bh[s], a1);
    a1 = MFMA32(w1h, Bl[s], a1);
    a1 = MFMA32(w1l, Bh[s], a1);
  }
}

template <int NS>
__device__ __forceinline__ void gemm2(const u16* __restrict__ Wh,
                                      const bf16x8* Bh, const bf16x8* Bl,
                                      int lane, f32x16& a0, f32x16& a1) {
#pragma unroll
  for (int s = 0; s < NS; ++s) {
    bf16x8 w0h = ldg16(Wh + ((s * 2 + 0) * 64 + lane) * 8);
    bf16x8 w1h = ldg16(Wh + ((s * 2 + 1) * 64 + lane) * 8);
    a0 = MFMA32(w0h, Bh[s], a0);
    a0 = MFMA32(w0h, Bl[s], a0);
    a1 = MFMA32(w1h, Bh[s], a1);
    a1 = MFMA32(w1h, Bl[s], a1);
  }
}

__global__ __launch_bounds__(384, 3) void pa_proj(
    const float* __restrict__ H, const float* __restrict__ L,
    const float* __restrict__ tb, const float* __restrict__ pb, const float* __restrict__ gb,
    const u16* __restrict__ Wth, const u16* __restrict__ Wph, const u16* __restrict__ Wpl,
    const u16* __restrict__ Wgh,
    u16* __restrict__ Qh, u16* __restrict__ Ql,
    u16* __restrict__ Kh, u16* __restrict__ V) {
  __shared__ float Rb[3 * 64 * 33];  // pair-merge buffer, stride 33 (2-way banks)
  int b = blockIdx.x >> 7;
  int t = blockIdx.x & 127;  // tile32
  int w = threadIdx.x >> 6;  // 0..5
  int lane = threadIdx.x & 63;
  int l31 = lane & 31, q2 = lane >> 5;
  int role = w >> 1, kh2 = w & 1;  // role: 0 theta, 1 phi, 2 g; kh2: k-half
  int n = t * 32 + l31;
  int base = t * 2048;  // u16 offset of this tile's fragment block (K/Q planes)

  f32x16 a0 = {}, a1 = {};
  if (role < 2) {
    bf16x8 Bh[4], Bl[4];
#pragma unroll
    for (int si = 0; si < 4; ++si) {
      int s = kh2 * 4 + si;
      const float* src = (s < 4) ? (H + (b * 64 + s * 16) * 4096)
                                 : (L + (b * 64 + (s - 4) * 16) * 4096);
      const float* pp = src + (q2 * 8) * 4096 + n;
      float xv[8];
#pragma unroll
      for (int j = 0; j < 8; ++j) xv[j] = pp[j * 4096];
      split8(xv, Bh[si], Bl[si]);
    }
    if (role == 0)
      gemm2<4>(Wth + kh2 * 4096, Bh, Bl, lane, a0, a1);
    else
      gemm3<4>(Wph + kh2 * 4096, Wpl + kh2 * 4096, Bh, Bl, lane, a0, a1);
  } else {
    bf16x8 Bh[2], Bl[2];
#pragma unroll
    for (int si = 0; si < 2; ++si) {
      int s = kh2 * 2 + si;
      const float* pp = L + (b * 64 + s * 16 + q2 * 8) * 4096 + n;
      float xv[8];
#pragma unroll
      for (int j = 0; j < 8; ++j) xv[j] = pp[j * 4096];
      split8(xv, Bh[si], Bl[si]);
    }
    gemm2<2>(Wgh + kh2 * 2048, Bh, Bl, lane, a0, a1);
  }

  float* rp = Rb + (role * 64 + lane) * 33;
  if (kh2 == 1) {
#pragma unroll
    for (int r = 0; r < 16; ++r) rp[r] = a0[r];
#pragma unroll
    for (int r = 0; r < 16; ++r) rp[16 + r] = a1[r];
  }
  __syncthreads();
  if (kh2 == 1) return;
#pragma unroll
  for (int r = 0; r < 16; ++r) a0[r] += rp[r];
#pragma unroll
  for (int r = 0; r < 16; ++r) a1[r] += rp[16 + r];

  if (role == 0) {
    store_qk_swz<false>(a0, a1, tb, Kh + b * 262144, (u16*)nullptr, base, l31, q2);
  } else if (role == 1) {
    store_qk_swz<true>(a0, a1, pb, Qh + b * 262144, Ql + b * 262144, base, l31, q2);
  } else {
    u16* Vb = V + b * 262144;
    int kch = (l31 >> 4) & 1, q2v = (l31 >> 3) & 1, jn = l31 & 7;
    (void)kch; (void)q2v; (void)jn;
#pragma unroll
    for (int mt = 0; mt < 2; ++mt) {
      const f32x16& A = mt ? a1 : a0;
#pragma unroll
      for (int rq = 0; rq < 4; ++rq) {
        int ch = mt * 32 + rq * 8 + q2 * 4;
        float4 bb = *reinterpret_cast<const float4*>(gb + ch);
        float vv[4] = {A[rq * 4 + 0] + bb.x, A[rq * 4 + 1] + bb.y,
                       A[rq * 4 + 2] + bb.z, A[rq * 4 + 3] + bb.w};
#pragma unroll
        for (int i2 = 0; i2 < 4; ++i2) {
          int c31 = rq * 8 + q2 * 4 + i2;
          int kch2 = (l31 >> 4) & 1, q2v2 = (l31 >> 3) & 1, jn2 = l31 & 7;
          int lane_v = c31 + 32 * q2v2;
          Vb[(((t * 2 + kch2) * 2 + mt) * 64 + lane_v) * 8 + jn2] = bbits(vv[i2]);
        }
      }
    }
  }
}

// ---------------------------------------------------------------------------
// Flash attention v7: m-tile 64 per block (halves L2 traffic vs m-tile 32:
// 264 MB total -> 7.6 us L2 floor). Grid 256 = (b, mt64) XCD-swizzled so each
// batch owns an XCD pair (per-XCD working set 2.6 MB < 4 MB L2). 512 thr = 8
// waves (n split 8-way, 16 iters x 32 keys), 2 waves/SIMD, (512,2) -> 256-reg
// cap (~230 live, no spill). S for both mb computed first so kh dies early ->
// explicit next-K prefetch into the dead regs; V issued at iter top.
// P C->B transform via lane^32 shfl (no LDS in loop). Fixed-M softmax,
// exact 8-way merge. C/D: col=lane&31 (m), row n = (r&3)+8*(r>>2)+4*q2.
// ---------------------------------------------------------------------------
__global__ __launch_bounds__(512, 2) void pa_flash(
    const u16* __restrict__ Qhg, const u16* __restrict__ Qlg,
    const u16* __restrict__ Khg, const u16* __restrict__ Vg, u16* __restrict__ E) {
  __shared__ float Obuf[64 * 67];  // [c][m] stride 67
  __shared__ float MLm[8 * 2 * 32];
  __shared__ float MLl[8 * 2 * 32];
  __shared__ float Lst[64];

  int tid = threadIdx.x;
  int w = tid >> 6, lane = tid & 63;
  int l31 = lane & 31, q2 = lane >> 5;
  int blk = blockIdx.x;
  int xcd = blk & 7;
  int b = xcd >> 1;                       // batch pinned to an XCD pair
  int mt = ((blk >> 3) << 1) | (xcd & 1); // 0..63 m-tile64 index
  int m0 = mt * 64;
  int bq = b * 4096;
  const u16* Qb = Qhg + b * 262144;
  const u16* Qlb = Qlg + b * 262144;
  const u16* Kb = Khg + b * 262144;
  const u16* Vb = Vg + b * 262144;

  // Q fragments in registers (coalesced fragment-order loads)
  bf16x8 qh[2][4], ql[2][4];
#pragma unroll
  for (int mb = 0; mb < 2; ++mb)
#pragma unroll
    for (int kc = 0; kc < 4; ++kc) {
      qh[mb][kc] = ldg16(Qb + (((mt * 2 + mb) * 4 + kc) * 64 + lane) * 8);
      ql[mb][kc] = ldg16(Qlb + (((mt * 2 + mb) * 4 + kc) * 64 + lane) * 8);
    }

  f32x16 accO[2][2] = {};  // [cbi][mb]
  float Mm[2] = {0.f, 0.f}, Ll[2] = {0.f, 0.f};

  bf16x8 kh[4];
#pragma unroll
  for (int kc = 0; kc < 4; ++kc) kh[kc] = ldg16(Kb + ((w * 4 + kc) * 64 + lane) * 8);

#pragma unroll 1
  for (int it = 0; it < 16; ++it) {
    int tile = it * 8 + w;

    // V for this tile (consumed at PV, issued early)
    bf16x8 vf[2][2];
#pragma unroll
    for (int kch = 0; kch < 2; ++kch)
#pragma unroll
      for (int cbi = 0; cbi < 2; ++cbi)
        vf[cbi][kch] = ldg16(Vb + (((tile * 2 + kch) * 2 + cbi) * 64 + lane) * 8);

    // QK for both mb -> kh dead after this
    f32x16 s[2];
#pragma unroll
    for (int mb = 0; mb < 2; ++mb) {
      f32x16 a = {};
#pragma unroll
      for (int kc = 0; kc < 4; ++kc) {
        a = MFMA32(kh[kc], qh[mb][kc], a);
        a = MFMA32(kh[kc], ql[mb][kc], a);
      }
      s[mb] = a;
    }
    // prefetch next K into the dead kh regs (in flight across softmax+PV)
    int tn = (it < 15) ? tile + 8 : tile;
#pragma unroll
    for (int kc = 0; kc < 4; ++kc) kh[kc] = ldg16(Kb + ((tn * 4 + kc) * 64 + lane) * 8);

#pragma unroll
    for (int mb = 0; mb < 2; ++mb) {
      if (it == 0) {  // freeze M from the wave's first tile (wave-uniform)
        float tmax = s[mb][0];
#pragma unroll
        for (int r = 1; r < 16; ++r) tmax = fmaxf(tmax, s[mb][r]);
        tmax = fmaxf(tmax, __shfl_xor(tmax, 32, 64));
        Mm[mb] = tmax;
      }
      float pv[16];
      float psum = 0.f;
#pragma unroll
      for (int r = 0; r < 16; ++r) {
        pv[r] = __expf(s[mb][r] - Mm[mb]);
        psum += pv[r];
      }
      psum += __shfl_xor(psum, 32, 64);
      Ll[mb] += psum;

      // C-layout quads -> bf16 pairs; quad q holds n = 8q + 4*q2 + 0..3
      unsigned pd[4][2];
#pragma unroll
      for (int q = 0; q < 4; ++q) {
        pd[q][0] = packbf(pv[q * 4 + 0], pv[q * 4 + 1]);
        pd[q][1] = packbf(pv[q * 4 + 2], pv[q * 4 + 3]);
      }
      unsigned xd[4][2];
#pragma unroll
      for (int q = 0; q < 4; ++q) {
        xd[q][0] = (unsigned)__shfl_xor((int)pd[q][0], 32, 64);
        xd[q][1] = (unsigned)__shfl_xor((int)pd[q][1], 32, 64);
      }
      // B-operand fragments: p0 = n 0..15 (k=q2*8+j), p1 = n 16..31
      uint4v u0, u1;
      u0.x = q2 ? xd[1][0] : pd[0][0];
      u0.y = q2 ? xd[1][1] : pd[0][1];
      u0.z = q2 ? pd[1][0] : xd[0][0];
      u0.w = q2 ? pd[1][1] : xd[0][1];
      u1.x = q2 ? xd[3][0] : pd[2][0];
      u1.y = q2 ? xd[3][1] : pd[2][1];
      u1.z = q2 ? pd[3][0] : xd[2][0];
      u1.w = q2 ? pd[3][1] : xd[2][1];
      bf16x8 p0 = __builtin_bit_cast(bf16x8, u0);
      bf16x8 p1 = __builtin_bit_cast(bf16x8, u1);

      accO[0][mb] = MFMA32(vf[0][0], p0, accO[0][mb]);
      accO[0][mb] = MFMA32(vf[0][1], p1, accO[0][mb]);
      accO[1][mb] = MFMA32(vf[1][0], p0, accO[1][mb]);
      accO[1][mb] = MFMA32(vf[1][1], p1, accO[1][mb]);
    }
  }

  // ---- exact merge of 8 waves' (O, M, l) ----
  if (q2 == 0) {
#pragma unroll
    for (int mb = 0; mb < 2; ++mb) {
      MLm[(w * 2 + mb) * 32 + l31] = Mm[mb];
      MLl[(w * 2 + mb) * 32 + l31] = Ll[mb];
    }
  }
  __syncthreads();
  float mysc[2];
#pragma unroll
  for (int mb = 0; mb < 2; ++mb) {
    float M = MLm[mb * 32 + l31];
    for (int ww = 1; ww < 8; ++ww) M = fmaxf(M, MLm[(ww * 2 + mb) * 32 + l31]);
    float ls = 0.f;
    for (int ww = 0; ww < 8; ++ww)
      ls += MLl[(ww * 2 + mb) * 32 + l31] * __expf(MLm[(ww * 2 + mb) * 32 + l31] - M);
    mysc[mb] = __expf(Mm[mb] - M);
    if (w == 0 && q2 == 0) Lst[mb * 32 + l31] = ls;
  }
  for (int ww = 0; ww < 8; ++ww) {
    if (w == ww) {
#pragma unroll
      for (int cbi = 0; cbi < 2; ++cbi)
#pragma unroll
        for (int mb = 0; mb < 2; ++mb) {
          float sc = mysc[mb];
#pragma unroll
          for (int r = 0; r < 16; ++r) {
            int c = cbi * 32 + (r & 3) + 8 * (r >> 2) + 4 * q2;
            int m = mb * 32 + l31;
            float* dst = &Obuf[c * 67 + m];
            float v = accO[cbi][mb][r] * sc;
            if (ww == 0)
              *dst = v;
            else
              *dst += v;
          }
        }
    }
    __syncthreads();
  }
  // write E[b][m][c] bf16 (spatial-major for the conv's B-operand)
  int em = tid >> 3, ec0 = (tid & 7) * 8;
  float invl = 1.0f / Lst[em];
  float vals[8];
#pragma unroll
  for (int j = 0; j < 8; ++j) vals[j] = Obuf[(ec0 + j) * 67 + em] * invl;
  uint4v u0;
  u0.x = packbf(vals[0], vals[1]);
  u0.y = packbf(vals[2], vals[3]);
  u0.z = packbf(vals[4], vals[5]);
  u0.w = packbf(vals[6], vals[7]);
  *reinterpret_cast<uint4v*>(E + (bq + m0 + em) * 64 + ec0) = u0;
}

// ---------------------------------------------------------------------------
// Conv3x3(SAME)+BN+ReLU+residual as shifted MFMA GEMMs.
// Block = (b, row y), 512 thr = 8 waves: (cbi, mb, ks); ks splits the
// 36-MFMA reduction in half -> 2 waves/SIMD; pair-merge via LDS.
// Wt in fragment order (coalesced); two MFMA chains per wave.
// ---------------------------------------------------------------------------
__global__ __launch_bounds__(512) void pa_conv(
    const u16* __restrict__ E, const u16* __restrict__ Wt,
    const float* __restrict__ bnA, const float* __restrict__ bnB,
    const float* __restrict__ H, float* __restrict__ out) {
  __shared__ u16 Er[3][66 * 68];
  __shared__ float Rbuf[4][64 * 17];
  int tid = threadIdx.x;
  int blk = blockIdx.x;
  int b = blk >> 6, y = blk & 63;
  int lane = tid & 63;
  int l31 = lane & 31, q2 = lane >> 5;
  int wv = tid >> 6;
  int ks = wv & 1, mb = (wv >> 1) & 1, cbi = wv >> 2;
  int s0 = (y == 0) ? 1 : 0;
  int s1 = (y == 63) ? 1 : 2;

  for (int s = s0; s <= s1; ++s) {
    int yy = y + s - 1;
    int x = tid >> 3, co = (tid & 7) * 8;
    const uint2v* src = reinterpret_cast<const uint2v*>(E + ((b * 4096 + yy * 64 + x) * 64 + co));
    uint2v a = src[0], b4 = src[1];
    u16* d = &Er[s][(x + 1) * 68 + co];
    *reinterpret_cast<uint2v*>(d) = a;
    *reinterpret_cast<uint2v*>(d + 4) = b4;
  }
  if (tid < 96) {  // zero x-halo columns
    int s = tid >> 5, side = (tid >> 4) & 1, co = (tid & 15) * 4;
    uint2v z;
    z.x = 0;
    z.y = 0;
    *reinterpret_cast<uint2v*>(&Er[s][(side ? 65 : 0) * 68 + co]) = z;
  }
  __syncthreads();

  f32x16 a0 = {}, a1 = {};
  for (int s = s0; s <= s1; ++s) {
#pragma unroll
    for (int dx = 0; dx < 3; ++dx) {
      int s3 = s * 3 + dx;
      int kcA = ks * 2, kcB = ks * 2 + 1;
      bf16x8 wa = ldg16(Wt + (((s3 * 4 + kcA) * 2 + cbi) * 64 + lane) * 8);
      bf16x8 wb = ldg16(Wt + (((s3 * 4 + kcB) * 2 + cbi) * 64 + lane) * 8);
      bf16x8 ea = ld_p8(&Er[s][(mb * 32 + l31 + dx) * 68 + kcA * 16 + q2 * 8]);
      bf16x8 eb = ld_p8(&Er[s][(mb * 32 + l31 + dx) * 68 + kcB * 16 + q2 * 8]);
      a0 = MFMA32(wa, ea, a0);
      a1 = MFMA32(wb, eb, a1);
    }
  }
  int p = cbi * 2 + mb;
  if (ks == 1) {
#pragma unroll
    for (int r = 0; r < 16; ++r) Rbuf[p][lane * 17 + r] = a0[r] + a1[r];
  }
  __syncthreads();
  if (ks == 0) {
#pragma unroll
    for (int r = 0; r < 16; ++r) {
      int c = cbi * 32 + (r & 3) + 8 * (r >> 2) + 4 * q2;
      int x = mb * 32 + l31;
      float v = a0[r] + a1[r] + Rbuf[p][lane * 17 + r];
      v = v * bnA[c] + bnB[c];
      v = fmaxf(v, 0.f);
      int idx = ((b * 64 + c) * 64 + y) * 64 + x;
      out[idx] = H[idx] + v;
    }
  }
}

// ---------------------------------------------------------------------------
extern "C" void kernel_launch(void* const* d_in, const int* in_sizes, int n_in,
                              void* d_out, int out_size, void* d_ws, size_t ws_size,
                              hipStream_t stream) {
  (void)in_sizes; (void)n_in; (void)out_size; (void)ws_size;
  const float* H = (const float*)d_in[0];
  const float* L = (const float*)d_in[1];
  const float* tw = (const float*)d_in[2];
  const float* tb = (const float*)d_in[3];
  const float* pw = (const float*)d_in[4];
  const float* pb = (const float*)d_in[5];
  const float* gw = (const float*)d_in[6];
  const float* gb = (const float*)d_in[7];
  const float* cw = (const float*)d_in[8];
  const float* cb = (const float*)d_in[9];
  const float* gamma = (const float*)d_in[10];
  const float* beta = (const float*)d_in[11];
  const float* mean = (const float*)d_in[12];
  const float* var = (const float*)d_in[13];

  const int NC = 16384 * 64;  // 1M u16 per plane (4 b x 262144)
  u16* Qh = (u16*)d_ws;
  u16* Ql = Qh + NC;
  u16* Kh = Ql + NC;
  u16* Vv = Kh + NC;
  u16* Eb = Vv + NC;
  u16* Wt = Eb + NC;                  // 36864 u16
  float* bnA = (float*)(Wt + 36864);  // 64 f32
  float* bnB = bnA + 64;              // 64 f32
  u16* Wth = (u16*)(bnB + 64);
  u16* Wtl = Wth + 8192;
  u16* Wph = Wtl + 8192;
  u16* Wpl = Wph + 8192;
  u16* Wgh = Wpl + 8192;  // 4096
  u16* Wgl = Wgh + 4096;  // 4096

  pa_prep<<<144, 256, 0, stream>>>(cw, cb, gamma, beta, mean, var, tw, pw, gw,
                                   Wt, bnA, bnB, Wth, Wtl, Wph, Wpl, Wgh, Wgl);
  pa_proj<<<512, 384, 0, stream>>>(H, L, tb, pb, gb, Wth, Wph, Wpl, Wgh,
                                   Qh, Ql, Kh, Vv);
  pa_flash<<<256, 512, 0, stream>>>(Qh, Ql, Kh, Vv, Eb);
  pa_conv<<<256, 512, 0, stream>>>(Eb, Wt, bnA, bnB, H, (float*)d_out);
}

// Round 8
// 134.800 us; speedup vs baseline: 1.0099x; 1.0099x over previous
//
#include <hip/hip_runtime.h>

typedef __bf16 bf16;
typedef unsigned short u16;
typedef __attribute__((ext_vector_type(8))) __bf16 bf16x8;
typedef __attribute__((ext_vector_type(16))) float f32x16;
typedef __attribute__((ext_vector_type(2))) unsigned int uint2v;
typedef __attribute__((ext_vector_type(4))) unsigned int uint4v;

#define MFMA32(a, b, c) __builtin_amdgcn_mfma_f32_32x32x16_bf16(a, b, c, 0, 0, 0)

__device__ __forceinline__ u16 bbits(float f) {
  bf16 h = (bf16)f;
  return __builtin_bit_cast(u16, h);
}
__device__ __forceinline__ float bf2f(u16 u) {
  return (float)__builtin_bit_cast(bf16, u);
}
__device__ __forceinline__ bf16x8 ldg16(const u16* p) {
  return *reinterpret_cast<const bf16x8*>(p);  // 16B-aligned by construction
}
// 8-byte-aligned read of 8 bf16 as two b64s (for 8B-aligned LDS rows)
__device__ __forceinline__ bf16x8 ld_p8(const u16* p) {
  uint2v a = *reinterpret_cast<const uint2v*>(p);
  uint2v b = *reinterpret_cast<const uint2v*>(p + 4);
  uint4v u;
  u.x = a.x; u.y = a.y; u.z = b.x; u.w = b.y;
  return __builtin_bit_cast(bf16x8, u);
}
__device__ __forceinline__ unsigned packbf(float a, float b) {
  return (unsigned)bbits(a) | ((unsigned)bbits(b) << 16);
}
// split 8 fp32 into hi/lo bf16x8 fragments
__device__ __forceinline__ void split8(const float* xv, bf16x8& hi, bf16x8& lo) {
  uint4v hv, lv;
#pragma unroll
  for (int jp = 0; jp < 4; ++jp) {
    float a0 = xv[2 * jp], a1 = xv[2 * jp + 1];
    u16 h0 = bbits(a0), h1 = bbits(a1);
    u16 l0 = bbits(a0 - bf2f(h0)), l1 = bbits(a1 - bf2f(h1));
    unsigned hh = (unsigned)h0 | ((unsigned)h1 << 16);
    unsigned ll = (unsigned)l0 | ((unsigned)l1 << 16);
    if (jp == 0) { hv.x = hh; lv.x = ll; }
    else if (jp == 1) { hv.y = hh; lv.y = ll; }
    else if (jp == 2) { hv.z = hh; lv.z = ll; }
    else { hv.w = hh; lv.w = ll; }
  }
  hi = __builtin_bit_cast(bf16x8, hv);
  lo = __builtin_bit_cast(bf16x8, lv);
}

// ===========================================================================
// SWIZZLED ("fragment-order") layouts — every MFMA fragment load is
// ldg16(base + (frag*64 + lane)*8): 64 lanes x 16B contiguous = coalesced.
//  K/Q planes (per b):  [tile n32][kc 0..3][lane][j]: pos=tile*32+(lane&31),
//     ch = kc*16+(lane>>5)*8+j
//  V plane (per b): [tile n32][kch][cbi][lane][j]: c=cbi*32+(lane&31),
//     n = tile*32+kch*16+(lane>>5)*8+j
//  conv Wt: [s3dx][kc][cbi][lane][j]
// ===========================================================================

// ---------------------------------------------------------------------------
// Projections v4 (prep fused): grid 512 = (b, tile32), 6 waves = 3 roles x
// 2 k-halves; pair-merge via LDS. 1x1 weights split hi/lo from fp32
// IN-REGISTER (2x float4 contiguous row loads + split8 — identical math to
// the old prep kernel). Tail: conv-weight swizzle + BN fold, one element per
// thread (consumed only by the later pa_conv dispatch -> ordering safe).
// theta/g 2-term split, phi 3-term.
// ---------------------------------------------------------------------------
template <bool LO>
__device__ __forceinline__ void store_qk_swz(const f32x16& a0, const f32x16& a1,
                                             const float* __restrict__ bias,
                                             u16* __restrict__ Hi, u16* __restrict__ Lo,
                                             int base, int l31, int q2) {
#pragma unroll
  for (int mt = 0; mt < 2; ++mt) {
    const f32x16& A = mt ? a1 : a0;
#pragma unroll
    for (int rq = 0; rq < 4; ++rq) {
      int ch = mt * 32 + rq * 8 + q2 * 4;
      float4 bb = *reinterpret_cast<const float4*>(bias + ch);
      float v0 = A[rq * 4 + 0] + bb.x;
      float v1 = A[rq * 4 + 1] + bb.y;
      float v2 = A[rq * 4 + 2] + bb.z;
      float v3 = A[rq * 4 + 3] + bb.w;
      int off = base + ((mt * 2 + (rq >> 1)) * 64 + l31 + 32 * (rq & 1)) * 8 + q2 * 4;
      u16 h0 = bbits(v0), h1 = bbits(v1), h2 = bbits(v2), h3 = bbits(v3);
      uint2v hv;
      hv.x = (unsigned)h0 | ((unsigned)h1 << 16);
      hv.y = (unsigned)h2 | ((unsigned)h3 << 16);
      *reinterpret_cast<uint2v*>(Hi + off) = hv;
      if (LO) {
        u16 l0 = bbits(v0 - bf2f(h0)), l1 = bbits(v1 - bf2f(h1));
        u16 l2 = bbits(v2 - bf2f(h2)), l3 = bbits(v3 - bf2f(h3));
        uint2v lv;
        lv.x = (unsigned)l0 | ((unsigned)l1 << 16);
        lv.y = (unsigned)l2 | ((unsigned)l3 << 16);
        *reinterpret_cast<uint2v*>(Lo + off) = lv;
      }
    }
  }
}

__device__ __forceinline__ void wfrag_f32(const float* __restrict__ W, int row, int inb,
                                          int stride, bf16x8& h, bf16x8& l) {
  const float* p = W + row * stride + inb;
  float xv[8];
  *reinterpret_cast<float4*>(xv) = *reinterpret_cast<const float4*>(p);
  *reinterpret_cast<float4*>(xv + 4) = *reinterpret_cast<const float4*>(p + 4);
  split8(xv, h, l);
}

__global__ __launch_bounds__(384, 3) void pa_proj(
    const float* __restrict__ H, const float* __restrict__ L,
    const float* __restrict__ tw, const float* __restrict__ tb,
    const float* __restrict__ pw, const float* __restrict__ pb,
    const float* __restrict__ gw, const float* __restrict__ gb,
    const float* __restrict__ cw, const float* __restrict__ cbias,
    const float* __restrict__ gamma, const float* __restrict__ beta,
    const float* __restrict__ mean, const float* __restrict__ var,
    u16* __restrict__ Qh, u16* __restrict__ Ql,
    u16* __restrict__ Kh, u16* __restrict__ V,
    u16* __restrict__ Wt, float* __restrict__ bnA, float* __restrict__ bnB) {
  __shared__ float Rb[3 * 64 * 33];  // pair-merge buffer, stride 33
  int tid = threadIdx.x;
  int b = blockIdx.x >> 7;
  int t = blockIdx.x & 127;  // tile32
  int w = tid >> 6;          // 0..5
  int lane = tid & 63;
  int l31 = lane & 31, q2 = lane >> 5;
  int role = w >> 1, kh2 = w & 1;  // role: 0 theta, 1 phi, 2 g; kh2: k-half
  int n = t * 32 + l31;
  int base = t * 2048;

  // ---- fused prep tail (conv Wt swizzle + BN fold), 1 elem/thread ----
  {
    int gid = blockIdx.x * 384 + tid;
    if (gid < 36864) {
      int j = gid & 7, ln = (gid >> 3) & 63, cbi = (gid >> 9) & 1;
      int kc = (gid >> 10) & 3, s = gid >> 12;
      int co = cbi * 32 + (ln & 31);
      int ci = kc * 16 + ((ln >> 5) & 1) * 8 + j;
      Wt[gid] = bbits(cw[(co * 64 + ci) * 9 + s]);
    } else if (gid < 36928) {
      int c = gid - 36864;
      float rs = rsqrtf(var[c] + 1e-5f);
      float A = gamma[c] * rs;
      bnA[c] = A;
      bnB[c] = (cbias[c] - mean[c]) * A + beta[c];
    }
  }

  f32x16 a0 = {}, a1 = {};
  if (role < 2) {
    bf16x8 Bh[4], Bl[4];
#pragma unroll
    for (int si = 0; si < 4; ++si) {
      int s = kh2 * 4 + si;
      const float* src = (s < 4) ? (H + (b * 64 + s * 16) * 4096)
                                 : (L + (b * 64 + (s - 4) * 16) * 4096);
      const float* pp = src + (q2 * 8) * 4096 + n;
      float xv[8];
#pragma unroll
      for (int j = 0; j < 8; ++j) xv[j] = pp[j * 4096];
      split8(xv, Bh[si], Bl[si]);
    }
    const float* W = role ? pw : tw;
#pragma unroll
    for (int si = 0; si < 4; ++si) {
      int inb = (kh2 * 4 + si) * 16 + q2 * 8;
      bf16x8 w0h, w0l, w1h, w1l;
      wfrag_f32(W, l31, inb, 128, w0h, w0l);
      wfrag_f32(W, 32 + l31, inb, 128, w1h, w1l);
      a0 = MFMA32(w0h, Bh[si], a0);
      a0 = MFMA32(w0h, Bl[si], a0);
      a1 = MFMA32(w1h, Bh[si], a1);
      a1 = MFMA32(w1h, Bl[si], a1);
      if (role == 1) {  // phi keeps the 3rd (w_lo * x_hi) term
        a0 = MFMA32(w0l, Bh[si], a0);
        a1 = MFMA32(w1l, Bh[si], a1);
      }
    }
  } else {
    bf16x8 Bh[2], Bl[2];
#pragma unroll
    for (int si = 0; si < 2; ++si) {
      int s = kh2 * 2 + si;
      const float* pp = L + (b * 64 + s * 16 + q2 * 8) * 4096 + n;
      float xv[8];
#pragma unroll
      for (int j = 0; j < 8; ++j) xv[j] = pp[j * 4096];
      split8(xv, Bh[si], Bl[si]);
    }
#pragma unroll
    for (int si = 0; si < 2; ++si) {
      int inb = (kh2 * 2 + si) * 16 + q2 * 8;
      bf16x8 w0h, w0l, w1h, w1l;
      wfrag_f32(gw, l31, inb, 64, w0h, w0l);
      wfrag_f32(gw, 32 + l31, inb, 64, w1h, w1l);
      a0 = MFMA32(w0h, Bh[si], a0);
      a0 = MFMA32(w0h, Bl[si], a0);
      a1 = MFMA32(w1h, Bh[si], a1);
      a1 = MFMA32(w1h, Bl[si], a1);
    }
  }

  float* rp = Rb + (role * 64 + lane) * 33;
  if (kh2 == 1) {
#pragma unroll
    for (int r = 0; r < 16; ++r) rp[r] = a0[r];
#pragma unroll
    for (int r = 0; r < 16; ++r) rp[16 + r] = a1[r];
  }
  __syncthreads();
  if (kh2 == 1) return;
#pragma unroll
  for (int r = 0; r < 16; ++r) a0[r] += rp[r];
#pragma unroll
  for (int r = 0; r < 16; ++r) a1[r] += rp[16 + r];

  if (role == 0) {
    store_qk_swz<false>(a0, a1, tb, Kh + b * 262144, (u16*)nullptr, base, l31, q2);
  } else if (role == 1) {
    store_qk_swz<true>(a0, a1, pb, Qh + b * 262144, Ql + b * 262144, base, l31, q2);
  } else {
    u16* Vb = V + b * 262144;
    int kch = (l31 >> 4) & 1, q2v = (l31 >> 3) & 1, jn = l31 & 7;
#pragma unroll
    for (int mt = 0; mt < 2; ++mt) {
      const f32x16& A = mt ? a1 : a0;
#pragma unroll
      for (int rq = 0; rq < 4; ++rq) {
        int ch = mt * 32 + rq * 8 + q2 * 4;
        float4 bb = *reinterpret_cast<const float4*>(gb + ch);
        float vv[4] = {A[rq * 4 + 0] + bb.x, A[rq * 4 + 1] + bb.y,
                       A[rq * 4 + 2] + bb.z, A[rq * 4 + 3] + bb.w};
#pragma unroll
        for (int i2 = 0; i2 < 4; ++i2) {
          int c31 = rq * 8 + q2 * 4 + i2;
          int lane_v = c31 + 32 * q2v;
          Vb[(((t * 2 + kch) * 2 + mt) * 64 + lane_v) * 8 + jn] = bbits(vv[i2]);
        }
      }
    }
  }
}

// ---------------------------------------------------------------------------
// Flash attention v8: m-tile 64, grid 256 = (b, mt64) XCD-swizzled, 512 thr
// = 8 waves (n 8-way, 16 iters x 32 keys), (512,2). Fragment-order K/Q/V
// loads; K prefetch into dead regs; P C->B via lane^32 shfl (no loop LDS).
// Fixed-M softmax + exact merge. Merge is now a REGION TREE (5 barriers vs
// 10): waves 4-7 write 4 LDS regions, waves 0-3 add, one thread-parallel
// 4->1 add, output. LDS ~69 KB (1 block/CU).
// C/D: col=lane&31 (m), row n = (r&3)+8*(r>>2)+4*q2.
// ---------------------------------------------------------------------------
__global__ __launch_bounds__(512, 2) void pa_flash(
    const u16* __restrict__ Qhg, const u16* __restrict__ Qlg,
    const u16* __restrict__ Khg, const u16* __restrict__ Vg, u16* __restrict__ E) {
  __shared__ float Reg[4][64 * 65];  // [region][c*65+m]
  __shared__ float MLm[8 * 2 * 32];
  __shared__ float MLl[8 * 2 * 32];
  __shared__ float Lst[64];

  int tid = threadIdx.x;
  int w = tid >> 6, lane = tid & 63;
  int l31 = lane & 31, q2 = lane >> 5;
  int blk = blockIdx.x;
  int xcd = blk & 7;
  int b = xcd >> 1;                        // batch pinned to an XCD pair
  int mt = ((blk >> 3) << 1) | (xcd & 1);  // 0..63 m-tile64 index
  int m0 = mt * 64;
  int bq = b * 4096;
  const u16* Qb = Qhg + b * 262144;
  const u16* Qlb = Qlg + b * 262144;
  const u16* Kb = Khg + b * 262144;
  const u16* Vb = Vg + b * 262144;

  bf16x8 qh[2][4], ql[2][4];
#pragma unroll
  for (int mb = 0; mb < 2; ++mb)
#pragma unroll
    for (int kc = 0; kc < 4; ++kc) {
      qh[mb][kc] = ldg16(Qb + (((mt * 2 + mb) * 4 + kc) * 64 + lane) * 8);
      ql[mb][kc] = ldg16(Qlb + (((mt * 2 + mb) * 4 + kc) * 64 + lane) * 8);
    }

  f32x16 accO[2][2] = {};  // [cbi][mb]
  float Mm[2] = {0.f, 0.f}, Ll[2] = {0.f, 0.f};

  bf16x8 kh[4];
#pragma unroll
  for (int kc = 0; kc < 4; ++kc) kh[kc] = ldg16(Kb + ((w * 4 + kc) * 64 + lane) * 8);

#pragma unroll 1
  for (int it = 0; it < 16; ++it) {
    int tile = it * 8 + w;

    bf16x8 vf[2][2];
#pragma unroll
    for (int kch = 0; kch < 2; ++kch)
#pragma unroll
      for (int cbi = 0; cbi < 2; ++cbi)
        vf[cbi][kch] = ldg16(Vb + (((tile * 2 + kch) * 2 + cbi) * 64 + lane) * 8);

    f32x16 s[2];
#pragma unroll
    for (int mb = 0; mb < 2; ++mb) {
      f32x16 a = {};
#pragma unroll
      for (int kc = 0; kc < 4; ++kc) {
        a = MFMA32(kh[kc], qh[mb][kc], a);
        a = MFMA32(kh[kc], ql[mb][kc], a);
      }
      s[mb] = a;
    }
    int tn = (it < 15) ? tile + 8 : tile;
#pragma unroll
    for (int kc = 0; kc < 4; ++kc) kh[kc] = ldg16(Kb + ((tn * 4 + kc) * 64 + lane) * 8);

#pragma unroll
    for (int mb = 0; mb < 2; ++mb) {
      if (it == 0) {  // freeze M from the wave's first tile (wave-uniform)
        float tmax = s[mb][0];
#pragma unroll
        for (int r = 1; r < 16; ++r) tmax = fmaxf(tmax, s[mb][r]);
        tmax = fmaxf(tmax, __shfl_xor(tmax, 32, 64));
        Mm[mb] = tmax;
      }
      float pv[16];
      float psum = 0.f;
#pragma unroll
      for (int r = 0; r < 16; ++r) {
        pv[r] = __expf(s[mb][r] - Mm[mb]);
        psum += pv[r];
      }
      psum += __shfl_xor(psum, 32, 64);
      Ll[mb] += psum;

      unsigned pd[4][2];
#pragma unroll
      for (int q = 0; q < 4; ++q) {
        pd[q][0] = packbf(pv[q * 4 + 0], pv[q * 4 + 1]);
        pd[q][1] = packbf(pv[q * 4 + 2], pv[q * 4 + 3]);
      }
      unsigned xd[4][2];
#pragma unroll
      for (int q = 0; q < 4; ++q) {
        xd[q][0] = (unsigned)__shfl_xor((int)pd[q][0], 32, 64);
        xd[q][1] = (unsigned)__shfl_xor((int)pd[q][1], 32, 64);
      }
      uint4v u0, u1;
      u0.x = q2 ? xd[1][0] : pd[0][0];
      u0.y = q2 ? xd[1][1] : pd[0][1];
      u0.z = q2 ? pd[1][0] : xd[0][0];
      u0.w = q2 ? pd[1][1] : xd[0][1];
      u1.x = q2 ? xd[3][0] : pd[2][0];
      u1.y = q2 ? xd[3][1] : pd[2][1];
      u1.z = q2 ? pd[3][0] : xd[2][0];
      u1.w = q2 ? pd[3][1] : xd[2][1];
      bf16x8 p0 = __builtin_bit_cast(bf16x8, u0);
      bf16x8 p1 = __builtin_bit_cast(bf16x8, u1);

      accO[0][mb] = MFMA32(vf[0][0], p0, accO[0][mb]);
      accO[0][mb] = MFMA32(vf[0][1], p1, accO[0][mb]);
      accO[1][mb] = MFMA32(vf[1][0], p0, accO[1][mb]);
      accO[1][mb] = MFMA32(vf[1][1], p1, accO[1][mb]);
    }
  }

  // ---- exact merge: ML exchange, then region tree ----
  if (q2 == 0) {
#pragma unroll
    for (int mb = 0; mb < 2; ++mb) {
      MLm[(w * 2 + mb) * 32 + l31] = Mm[mb];
      MLl[(w * 2 + mb) * 32 + l31] = Ll[mb];
    }
  }
  __syncthreads();
  float mysc[2];
#pragma unroll
  for (int mb = 0; mb < 2; ++mb) {
    float M = MLm[mb * 32 + l31];
    for (int ww = 1; ww < 8; ++ww) M = fmaxf(M, MLm[(ww * 2 + mb) * 32 + l31]);
    float ls = 0.f;
    for (int ww = 0; ww < 8; ++ww)
      ls += MLl[(ww * 2 + mb) * 32 + l31] * __expf(MLm[(ww * 2 + mb) * 32 + l31] - M);
    mysc[mb] = __expf(Mm[mb] - M);
    if (w == 0 && q2 == 0) Lst[mb * 32 + l31] = ls;
  }
  // phase A: waves 4..7 write region w-4
  if (w >= 4) {
    float* R = Reg[w - 4];
#pragma unroll
    for (int cbi = 0; cbi < 2; ++cbi)
#pragma unroll
      for (int mb = 0; mb < 2; ++mb) {
        float sc = mysc[mb];
#pragma unroll
        for (int r = 0; r < 16; ++r) {
          int c = cbi * 32 + (r & 3) + 8 * (r >> 2) + 4 * q2;
          int m = mb * 32 + l31;
          R[c * 65 + m] = accO[cbi][mb][r] * sc;
        }
      }
  }
  __syncthreads();
  // phase B: waves 0..3 add into region w
  if (w < 4) {
    float* R = Reg[w];
#pragma unroll
    for (int cbi = 0; cbi < 2; ++cbi)
#pragma unroll
      for (int mb = 0; mb < 2; ++mb) {
        float sc = mysc[mb];
#pragma unroll
        for (int r = 0; r < 16; ++r) {
          int c = cbi * 32 + (r & 3) + 8 * (r >> 2) + 4 * q2;
          int m = mb * 32 + l31;
          R[c * 65 + m] += accO[cbi][mb][r] * sc;
        }
      }
  }
  __syncthreads();
  // phase C: thread-parallel 4->1 add into region 0
  for (int i = tid; i < 4096; i += 512) {
    int c = i >> 6, m = i & 63;
    int a = c * 65 + m;
    Reg[0][a] = (Reg[0][a] + Reg[1][a]) + (Reg[2][a] + Reg[3][a]);
  }
  __syncthreads();
  // output: E[b][m][c] bf16
  int em = tid >> 3, ec0 = (tid & 7) * 8;
  float invl = 1.0f / Lst[em];
  float vals[8];
#pragma unroll
  for (int j = 0; j < 8; ++j) vals[j] = Reg[0][(ec0 + j) * 65 + em] * invl;
  uint4v u0;
  u0.x = packbf(vals[0], vals[1]);
  u0.y = packbf(vals[2], vals[3]);
  u0.z = packbf(vals[4], vals[5]);
  u0.w = packbf(vals[6], vals[7]);
  *reinterpret_cast<uint4v*>(E + (bq + m0 + em) * 64 + ec0) = u0;
}

// ---------------------------------------------------------------------------
// Conv3x3(SAME)+BN+ReLU+residual as shifted MFMA GEMMs.
// Block = (b, row y), 512 thr = 8 waves: (cbi, mb, ks); ks splits the
// 36-MFMA reduction in half -> 2 waves/SIMD; pair-merge via LDS.
// Wt in fragment order (written by pa_proj's fused prep tail).
// ---------------------------------------------------------------------------
__global__ __launch_bounds__(512) void pa_conv(
    const u16* __restrict__ E, const u16* __restrict__ Wt,
    const float* __restrict__ bnA, const float* __restrict__ bnB,
    const float* __restrict__ H, float* __restrict__ out) {
  __shared__ u16 Er[3][66 * 68];
  __shared__ float Rbuf[4][64 * 17];
  int tid = threadIdx.x;
  int blk = blockIdx.x;
  int b = blk >> 6, y = blk & 63;
  int lane = tid & 63;
  int l31 = lane & 31, q2 = lane >> 5;
  int wv = tid >> 6;
  int ks = wv & 1, mb = (wv >> 1) & 1, cbi = wv >> 2;
  int s0 = (y == 0) ? 1 : 0;
  int s1 = (y == 63) ? 1 : 2;

  for (int s = s0; s <= s1; ++s) {
    int yy = y + s - 1;
    int x = tid >> 3, co = (tid & 7) * 8;
    const uint2v* src = reinterpret_cast<const uint2v*>(E + ((b * 4096 + yy * 64 + x) * 64 + co));
    uint2v a = src[0], b4 = src[1];
    u16* d = &Er[s][(x + 1) * 68 + co];
    *reinterpret_cast<uint2v*>(d) = a;
    *reinterpret_cast<uint2v*>(d + 4) = b4;
  }
  if (tid < 96) {  // zero x-halo columns
    int s = tid >> 5, side = (tid >> 4) & 1, co = (tid & 15) * 4;
    uint2v z;
    z.x = 0;
    z.y = 0;
    *reinterpret_cast<uint2v*>(&Er[s][(side ? 65 : 0) * 68 + co]) = z;
  }
  __syncthreads();

  f32x16 a0 = {}, a1 = {};
  for (int s = s0; s <= s1; ++s) {
#pragma unroll
    for (int dx = 0; dx < 3; ++dx) {
      int s3 = s * 3 + dx;
      int kcA = ks * 2, kcB = ks * 2 + 1;
      bf16x8 wa = ldg16(Wt + (((s3 * 4 + kcA) * 2 + cbi) * 64 + lane) * 8);
      bf16x8 wb = ldg16(Wt + (((s3 * 4 + kcB) * 2 + cbi) * 64 + lane) * 8);
      bf16x8 ea = ld_p8(&Er[s][(mb * 32 + l31 + dx) * 68 + kcA * 16 + q2 * 8]);
      bf16x8 eb = ld_p8(&Er[s][(mb * 32 + l31 + dx) * 68 + kcB * 16 + q2 * 8]);
      a0 = MFMA32(wa, ea, a0);
      a1 = MFMA32(wb, eb, a1);
    }
  }
  int p = cbi * 2 + mb;
  if (ks == 1) {
#pragma unroll
    for (int r = 0; r < 16; ++r) Rbuf[p][lane * 17 + r] = a0[r] + a1[r];
  }
  __syncthreads();
  if (ks == 0) {
#pragma unroll
    for (int r = 0; r < 16; ++r) {
      int c = cbi * 32 + (r & 3) + 8 * (r >> 2) + 4 * q2;
      int x = mb * 32 + l31;
      float v = a0[r] + a1[r] + Rbuf[p][lane * 17 + r];
      v = v * bnA[c] + bnB[c];
      v = fmaxf(v, 0.f);
      int idx = ((b * 64 + c) * 64 + y) * 64 + x;
      out[idx] = H[idx] + v;
    }
  }
}

// ---------------------------------------------------------------------------
extern "C" void kernel_launch(void* const* d_in, const int* in_sizes, int n_in,
                              void* d_out, int out_size, void* d_ws, size_t ws_size,
                              hipStream_t stream) {
  (void)in_sizes; (void)n_in; (void)out_size; (void)ws_size;
  const float* H = (const float*)d_in[0];
  const float* L = (const float*)d_in[1];
  const float* tw = (const float*)d_in[2];
  const float* tb = (const float*)d_in[3];
  const float* pw = (const float*)d_in[4];
  const float* pb = (const float*)d_in[5];
  const float* gw = (const float*)d_in[6];
  const float* gb = (const float*)d_in[7];
  const float* cw = (const float*)d_in[8];
  const float* cb = (const float*)d_in[9];
  const float* gamma = (const float*)d_in[10];
  const float* beta = (const float*)d_in[11];
  const float* mean = (const float*)d_in[12];
  const float* var = (const float*)d_in[13];

  const int NC = 16384 * 64;  // 1M u16 per plane (4 b x 262144)
  u16* Qh = (u16*)d_ws;
  u16* Ql = Qh + NC;
  u16* Kh = Ql + NC;
  u16* Vv = Kh + NC;
  u16* Eb = Vv + NC;
  u16* Wt = Eb + NC;                  // 36864 u16
  float* bnA = (float*)(Wt + 36864);  // 64 f32
  float* bnB = bnA + 64;              // 64 f32

  pa_proj<<<512, 384, 0, stream>>>(H, L, tw, tb, pw, pb, gw, gb,
                                   cw, cb, gamma, beta, mean, var,
                                   Qh, Ql, Kh, Vv, Wt, bnA, bnB);
  pa_flash<<<256, 512, 0, stream>>>(Qh, Ql, Kh, Vv, Eb);
  pa_conv<<<256, 512, 0, stream>>>(Eb, Wt, bnA, bnB, H, (float*)d_out);
}